// Round 12
// baseline (71.364 us; speedup 1.0000x reference)
//
#include <hip/hip_runtime.h>
#include <stdint.h>

#define N_CAND 462080   // 16*76*76*5
#define NBINS  2048
#define HIST_BLOCKS 32
#define COMPACT_BLOCKS 64
#define TARGET 256u
#define SMAX   1024
#define SCORE_THR 0.02f
#define NT 14440        // tiles of 32 candidates
#define DGRID 1792      // 7 blocks/CU * 256 CU
#define TILEF 2720      // floats per tile (32*85)
#define TILE4 680       // float4 per tile
// ctrl u32 indices, 64B apart (separate cache lines)
#define C_CNT 0    // compact count (hot atomic)
#define C_BIN 16   // cutoff bin
#define C_HD  32   // hist done-counter
#define C_CD  48   // compact done-counter

// ---------------- ws layout (bytes) ----------------
// ctrl      : 64 x u32       @ 0       end 256
// hist_part : 32 x 2048 u16  @ 256     end 131328
// lscore    : 1024 x f32     @ 131328  end 135424
// lidx      : 1024 x i32     @ 135424  end 139520
// scores    : N x f32        @ 139520  end 1987840  (~2 MB)
// No memset dispatch: decode block 0 re-arms both done-counters every call;
// hist's elected block zeroes C_CNT and always writes C_BIN.
// => no dependence on initial ws content (harness poisons ws to 0xAA).

typedef const __attribute__((address_space(1))) uint32_t* gas1_u32;
typedef __attribute__((address_space(3))) uint32_t*       las3_u32;
#define GLOAD_LDS16(g, l) __builtin_amdgcn_global_load_lds( \
    (gas1_u32)(const void*)(g), (las3_u32)(void*)(l), 16, 0, 0)

// stage one 32-candidate tile (680 float4): 10 full wave-rounds + 40-lane tail
// = 11 global_load_lds wave-instructions.
__device__ __forceinline__ void stage_tile(const float* feats, int tile,
                                           float* buf, int t)
{
    const float4* __restrict__ src = (const float4*)(feats + (size_t)tile * TILEF);
    float4* dst = (float4*)buf;
#pragma unroll
    for (int i = 0; i < 10; ++i)
        GLOAD_LDS16(src + i * 64 + t, dst + i * 64 + t);
    if (t < 40) GLOAD_LDS16(src + 640 + t, dst + 640 + t);
}

// ============ Kernel 1: decode — persistent waves, LDS double-buffer ============
// One wave/block, 7 blocks/CU (21.76 KB LDS). Each wave grid-strides over
// 32-candidate tiles: issue next tile's 11 global_load_lds, wait vmcnt(11)
// (previous tile's 11 retired -- vmcnt retires in issue order), compute.
// Channel-split: lanes c and c+32 each do 40 of candidate c's 80 classes.
__global__ __launch_bounds__(64) void decode_kernel(
    const float* __restrict__ feats,
    float* __restrict__ scores, unsigned int* __restrict__ ctrl)
{
    __shared__ __align__(16) float lds[2 * TILEF];   // 21760 B
    const int t = threadIdx.x;
    const int c = t & 31;        // candidate within tile
    const int h = t >> 5;        // class-half (0: k=5..44, 1: k=45..84)

    if (blockIdx.x == 0 && t == 0) { ctrl[C_HD] = 0u; ctrl[C_CD] = 0u; }  // re-arm

    int tile = blockIdx.x;
    stage_tile(feats, tile, lds, t);        // prologue -> buffer 0
    int parity = 0;
    while (tile < NT) {
        const int next = tile + DGRID;
        if (next < NT) {
            stage_tile(feats, next, lds + (parity ^ 1) * TILEF, t);
            asm volatile("s_waitcnt vmcnt(11)" ::: "memory");  // old tile's 11 retired
        } else {
            asm volatile("s_waitcnt vmcnt(0)" ::: "memory");
        }
        __builtin_amdgcn_sched_barrier(0);

        const float* f = lds + parity * TILEF + c * 85;  // stride 85: conflict-free
        const int kb = 5 + h * 40;

        // half-max over 40 class logits (4 accumulators)
        float m0 = f[kb + 0], m1 = f[kb + 1], m2 = f[kb + 2], m3 = f[kb + 3];
#pragma unroll
        for (int k = 4; k < 40; k += 4) {
            m0 = fmaxf(m0, f[kb + k + 0]);
            m1 = fmaxf(m1, f[kb + k + 1]);
            m2 = fmaxf(m2, f[kb + k + 2]);
            m3 = fmaxf(m3, f[kb + k + 3]);
        }
        float mloc = fmaxf(fmaxf(m0, m1), fmaxf(m2, m3));
        float mall = fmaxf(mloc, __shfl_xor(mloc, 32));   // full 80-class max

        // half-sum of exp(l - mall)
        float s0 = 0.f, s1 = 0.f, s2 = 0.f, s3 = 0.f;
#pragma unroll
        for (int k = 0; k < 40; k += 4) {
            s0 += __expf(f[kb + k + 0] - mall);
            s1 += __expf(f[kb + k + 1] - mall);
            s2 += __expf(f[kb + k + 2] - mall);
            s3 += __expf(f[kb + k + 3] - mall);
        }
        float sl = (s0 + s1) + (s2 + s3);
        float sall = sl + __shfl_xor(sl, 32);

        if (h == 0) {
            float conf = 1.0f / (1.0f + __expf(-f[4]));
            float score = conf / sall;                    // conf * max-softmax-prob
            scores[tile * 32 + c] = (score >= SCORE_THR) ? score : -1.0f;
        }
        parity ^= 1;
        tile = next;
    }
}

// ============ Kernel 2: histogram + (elected last block) cutoff scan ============
// t0-only fences: __syncthreads() drains vmcnt per wave (stores in this XCD's
// L2); one t0 __threadfence (wb) publishes before the election atomic; the
// elected block t0-fences (inv) after winning, barrier, then reads.
__global__ __launch_bounds__(1024) void hist_cutoff_kernel(
    const float* __restrict__ scores, unsigned short* __restrict__ hist_part,
    unsigned int* __restrict__ ctrl)
{
    __shared__ unsigned int lh[NBINS];          // 8 KB
    __shared__ unsigned int pa[1024], pb[1024]; // 8 KB ping-pong
    __shared__ int lastf;
    const int t = threadIdx.x;

    lh[2 * t] = 0u; lh[2 * t + 1] = 0u;
    __syncthreads();

    for (int i = blockIdx.x * 1024 + t; i < N_CAND; i += HIST_BLOCKS * 1024) {
        float s = scores[i];
        if (s >= SCORE_THR) {
            int bin = (int)(s * (float)NBINS);
            bin = bin > (NBINS - 1) ? (NBINS - 1) : bin;
            atomicAdd(&lh[bin], 1u);   // LDS atomic only
        }
    }
    __syncthreads();
    // store part as packed u32 (two u16 bins), coalesced
    unsigned int* outp = (unsigned int*)(hist_part + (size_t)blockIdx.x * NBINS);
    outp[t] = (lh[2 * t] & 0xFFFFu) | (lh[2 * t + 1] << 16);
    __syncthreads();                                   // vmcnt drained -> stores in L2

    if (t == 0) {
        __threadfence();                               // release: wb this XCD's L2
        unsigned old = atomicAdd(&ctrl[C_HD], 1u);
        lastf = (old == HIST_BLOCKS - 1) ? 1 : 0;
    }
    __syncthreads();
    if (!lastf) return;
    if (t == 0) __threadfence();                       // acquire: invalidate caches
    __syncthreads();

    // ---- cutoff scan (elected block) ----
    const unsigned int* hp32 = (const unsigned int*)hist_part;
    unsigned b0 = 0u, b1 = 0u;
#pragma unroll 4
    for (int p = 0; p < HIST_BLOCKS; ++p) {
        unsigned v = hp32[p * 1024 + t];
        b0 += v & 0xFFFFu;
        b1 += v >> 16;
    }
    lh[2 * t] = b0; lh[2 * t + 1] = b1;
    pa[t] = b0 + b1;
    __syncthreads();

    // inclusive suffix scan, ping-pong (10 barriers)
    unsigned int* srcb = pa; unsigned int* dstb = pb;
    for (int off = 1; off < 1024; off <<= 1) {
        unsigned v = srcb[t] + ((t + off < 1024) ? srcb[t + off] : 0u);
        dstb[t] = v;
        __syncthreads();
        unsigned int* tmp = srcb; srcb = dstb; dstb = tmp;
    }
    unsigned St = srcb[t];
    unsigned Sn = (t < 1023) ? srcb[t + 1] : 0u;

    if (t == 0) {
        ctrl[C_CNT] = 0u;                   // reset compact counter (next dispatch)
        if (St < TARGET) ctrl[C_BIN] = 0u;  // total < TARGET -> keep all valid
    }
    // unique crossing thread: b* = max{b : suffix(b) >= TARGET}
    if (St >= TARGET && Sn < TARGET) {
        unsigned run = Sn + lh[2 * t + 1];
        ctrl[C_BIN] = (run >= TARGET) ? (unsigned)(2 * t + 1) : (unsigned)(2 * t);
    }
}

// box decode for one candidate (matches reference formulas, fp32)
__device__ inline float4 decode_box(const float* __restrict__ feats,
                                    const float* __restrict__ anchors, int ci)
{
    int a = ci % 5;
    int cell = ci / 5;
    int gx = cell % 76;
    int gy = (cell / 76) % 76;
    const float* f = feats + (long long)ci * 85;
    float bx = (1.0f / (1.0f + __expf(-f[0])) + (float)gx) / 76.0f;
    float by = (1.0f / (1.0f + __expf(-f[1])) + (float)gy) / 76.0f;
    float bw = __expf(f[2]) * anchors[2 * a]     / 76.0f;
    float bh = __expf(f[3]) * anchors[2 * a + 1] / 76.0f;
    return make_float4(by - bh * 0.5f, bx - bw * 0.5f,
                       by + bh * 0.5f, bx + bw * 0.5f);  // y1,x1,y2,x2
}

// ============ Kernel 3: compact (grid-stride) + elected sort-free NMS ============
__global__ __launch_bounds__(1024) void compact_nms_kernel(
    const float* __restrict__ scores, unsigned int* __restrict__ ctrl,
    float* __restrict__ lscore, int* __restrict__ lidx,
    const float* __restrict__ feats, const float* __restrict__ anchors,
    float* __restrict__ out)
{
    __shared__ unsigned long long wkey[16];
    __shared__ unsigned long long bkey;
    __shared__ float4 bbox;
    __shared__ int lastf;
    const int t = threadIdx.x;

    // ---- compact phase (grid-stride) ----
    const int cut = (int)ctrl[C_BIN];   // written by previous dispatch: coherent
    for (int i = blockIdx.x * 1024 + t; i < N_CAND; i += COMPACT_BLOCKS * 1024) {
        float sw = scores[i];
        if (sw >= SCORE_THR) {
            int bin = (int)(sw * (float)NBINS);
            bin = bin > (NBINS - 1) ? (NBINS - 1) : bin;
            if (bin >= cut) {
                unsigned pos = atomicAdd(&ctrl[C_CNT], 1u);
                if (pos < SMAX) { lscore[pos] = sw; lidx[pos] = i; }
            }
        }
    }
    __syncthreads();                                   // vmcnt drained -> stores in L2
    if (t == 0) {
        __threadfence();                               // release
        unsigned old = atomicAdd(&ctrl[C_CD], 1u);
        lastf = (old == COMPACT_BLOCKS - 1) ? 1 : 0;
    }
    __syncthreads();
    if (!lastf) return;
    if (t == 0) __threadfence();                       // acquire
    __syncthreads();

    // ---- NMS phase (1024 threads, 1 candidate/thread) ----
    unsigned cnt = ctrl[C_CNT];
    int n = (cnt < (unsigned)SMAX) ? (int)cnt : SMAX;

    unsigned long long key = 0ull;
    float4 mb = make_float4(0.f, 0.f, 0.f, 0.f);
    float  msc = 0.f, mcls = 0.f;
    unsigned midx = 0xFFFFFFFFu;
    bool aliveb = false;
    if (t < n) {
        msc  = lscore[t];
        midx = (unsigned)lidx[t];
        key  = ((unsigned long long)__float_as_uint(msc) << 32)
             | (unsigned long long)(0xFFFFFFFFu - midx);   // score desc, idx asc
        mb   = decode_box(feats, anchors, (int)midx);
        // class argmax from L3-resident feats (first-index tie-break)
        const float* fc = feats + (size_t)midx * 85 + 5;
        float bm = fc[0]; int cb = 0;
#pragma unroll 4
        for (int k = 1; k < 80; ++k) {
            float v = fc[k];
            if (v > bm) { bm = v; cb = k; }
        }
        mcls = (float)cb;
        aliveb = true;
    }

    for (int r = 0; r < 10; ++r) {
        unsigned long long k0 = aliveb ? key : 0ull;
#pragma unroll
        for (int msk = 32; msk > 0; msk >>= 1) {
            unsigned long long o = __shfl_xor(k0, msk);
            k0 = (o > k0) ? o : k0;
        }
        if ((t & 63) == 0) wkey[t >> 6] = k0;
        __syncthreads();
        if (t < 16) {
            unsigned long long v = wkey[t];
#pragma unroll
            for (int msk = 8; msk > 0; msk >>= 1) {
                unsigned long long o = __shfl_xor(v, msk);
                v = (o > v) ? o : v;
            }
            if (t == 0) bkey = v;
        }
        __syncthreads();

        unsigned long long wk = bkey;
        bool have = (wk != 0ull);
        unsigned widx = have ? (0xFFFFFFFFu - (unsigned)(wk & 0xFFFFFFFFull)) : 0xFFFFFFFFu;

        if (have && aliveb && midx == widx) {   // unique winner thread
            bbox = mb;
            out[r * 6 + 0] = mb.x;
            out[r * 6 + 1] = mb.y;
            out[r * 6 + 2] = mb.z;
            out[r * 6 + 3] = mb.w;
            out[r * 6 + 4] = msc;
            out[r * 6 + 5] = mcls;
            aliveb = false;
        }
        if (!have && t == 0) {
#pragma unroll
            for (int q = 0; q < 6; ++q) out[r * 6 + q] = 0.f;
        }
        __syncthreads();                        // bbox visible to all

        if (have && aliveb) {
            float4 ab = bbox;
            float aarea = fmaxf(ab.z - ab.x, 0.f) * fmaxf(ab.w - ab.y, 0.f);
            float iy1 = fmaxf(ab.x, mb.x);
            float ix1 = fmaxf(ab.y, mb.y);
            float iy2 = fminf(ab.z, mb.z);
            float ix2 = fminf(ab.w, mb.w);
            float inter = fmaxf(iy2 - iy1, 0.f) * fmaxf(ix2 - ix1, 0.f);
            float carea = fmaxf(mb.z - mb.x, 0.f) * fmaxf(mb.w - mb.y, 0.f);
            float iou = inter / (aarea + carea - inter + 1e-9f);
            if (iou > 0.5f) aliveb = false;
        }
    }
}

extern "C" void kernel_launch(void* const* d_in, const int* in_sizes, int n_in,
                              void* d_out, int out_size, void* d_ws, size_t ws_size,
                              hipStream_t stream) {
    const float* feats   = (const float*)d_in[0];
    const float* anchors = (const float*)d_in[1];
    char* ws = (char*)d_ws;

    unsigned int*   ctrl      = (unsigned int*)(ws + 0);
    unsigned short* hist_part = (unsigned short*)(ws + 256);
    float*          lscore    = (float*)(ws + 131328);
    int*            lidx      = (int*)(ws + 135424);
    float*          scores    = (float*)(ws + 139520);
    float*          out       = (float*)d_out;

    decode_kernel      <<<DGRID, 64, 0, stream>>>(feats, scores, ctrl);
    hist_cutoff_kernel <<<HIST_BLOCKS, 1024, 0, stream>>>(scores, hist_part, ctrl);
    compact_nms_kernel <<<COMPACT_BLOCKS, 1024, 0, stream>>>(scores, ctrl, lscore, lidx,
                                                             feats, anchors, out);
}

// Round 13
// 70.010 us; speedup vs baseline: 1.0193x; 1.0193x over previous
//
#include <hip/hip_runtime.h>
#include <stdint.h>

#define N_CAND 462080   // 16*76*76*5
#define NBINS  2048
#define HIST_BLOCKS 32
#define COMPACT_BLOCKS 64
#define TARGET 256u
#define SMAX   1024
#define SCORE_THR 0.02f
#define NT 14440        // tiles of 32 candidates (exact: 14440*32 = 462080)
#define TILEF 2720      // floats per tile (32*85)
// ctrl u32 indices, 64B apart (separate cache lines)
#define C_CNT 0    // compact count (hot atomic)
#define C_BIN 16   // cutoff bin
#define C_HD  32   // hist done-counter
#define C_CD  48   // compact done-counter

// ---------------- ws layout (bytes) ----------------
// ctrl      : 64 x u32       @ 0       end 256
// hist_part : 32 x 2048 u16  @ 256     end 131328
// lscore    : 1024 x f32     @ 131328  end 135424
// lidx      : 1024 x i32     @ 135424  end 139520
// scores    : N x f32        @ 139520  end 1987840  (~2 MB)
// No memset dispatch: decode block 0 re-arms both done-counters every call;
// hist's elected block zeroes C_CNT and always writes C_BIN.
// => no dependence on initial ws content (harness poisons ws to 0xAA).

typedef const __attribute__((address_space(1))) uint32_t* gas1_u32;
typedef __attribute__((address_space(3))) uint32_t*       las3_u32;
#define GLOAD_LDS16(g, l) __builtin_amdgcn_global_load_lds( \
    (gas1_u32)(const void*)(g), (las3_u32)(void*)(l), 16, 0, 0)

// ============ Kernel 1: decode — one-shot, one wave, 32 cand, 14 blocks/CU ============
// 10.88 KB LDS -> 14 resident one-shot waves/CU (3.5/SIMD): block-level
// pipelining (HW backfills finished slots) hides the vmcnt(0) stall; R12's
// 1-deep software pipeline at 7 waves/CU was SLOWER (71 vs 59 us) -- the CU
// scheduler does this better than a depth-1 double-buffer.
// Channel-split: lanes c and c+32 each handle 40 of candidate c's 80 classes.
__global__ __launch_bounds__(64) void decode_kernel(
    const float* __restrict__ feats,
    float* __restrict__ scores, unsigned int* __restrict__ ctrl)
{
    __shared__ __align__(16) float lds[TILEF];   // 10880 B
    const int t = threadIdx.x;
    const int c = t & 31;        // candidate within tile
    const int h = t >> 5;        // class-half (0: k=5..44, 1: k=45..84)
    const int tile = blockIdx.x;

    if (tile == 0 && t == 0) { ctrl[C_HD] = 0u; ctrl[C_CD] = 0u; }  // re-arm

    // stage 680 float4 = 10 full wave-rounds + 40-lane tail (11 gload_lds)
    {
        const float4* __restrict__ src = (const float4*)(feats + (size_t)tile * TILEF);
        float4* dst = (float4*)lds;
#pragma unroll
        for (int i = 0; i < 10; ++i)
            GLOAD_LDS16(src + i * 64 + t, dst + i * 64 + t);
        if (t < 40) GLOAD_LDS16(src + 640 + t, dst + 640 + t);
    }
    asm volatile("s_waitcnt vmcnt(0)" ::: "memory");   // per-wave drain, no barrier
    __builtin_amdgcn_sched_barrier(0);

    const float* f = lds + c * 85;   // bank (c*21+k)%32 permutes; h-pair = free 2-way
    const int kb = 5 + h * 40;

    // half-max over 40 class logits (4 accumulators)
    float m0 = f[kb + 0], m1 = f[kb + 1], m2 = f[kb + 2], m3 = f[kb + 3];
#pragma unroll
    for (int k = 4; k < 40; k += 4) {
        m0 = fmaxf(m0, f[kb + k + 0]);
        m1 = fmaxf(m1, f[kb + k + 1]);
        m2 = fmaxf(m2, f[kb + k + 2]);
        m3 = fmaxf(m3, f[kb + k + 3]);
    }
    float mloc = fmaxf(fmaxf(m0, m1), fmaxf(m2, m3));
    float mall = fmaxf(mloc, __shfl_xor(mloc, 32));   // full 80-class max

    // half-sum of exp(l - mall)
    float s0 = 0.f, s1 = 0.f, s2 = 0.f, s3 = 0.f;
#pragma unroll
    for (int k = 0; k < 40; k += 4) {
        s0 += __expf(f[kb + k + 0] - mall);
        s1 += __expf(f[kb + k + 1] - mall);
        s2 += __expf(f[kb + k + 2] - mall);
        s3 += __expf(f[kb + k + 3] - mall);
    }
    float sl = (s0 + s1) + (s2 + s3);
    float sall = sl + __shfl_xor(sl, 32);

    if (h == 0) {
        float conf = 1.0f / (1.0f + __expf(-f[4]));
        float score = conf / sall;                    // conf * max-softmax-prob
        scores[tile * 32 + c] = (score >= SCORE_THR) ? score : -1.0f;
    }
}

// ============ Kernel 2: histogram + (elected last block) cutoff scan ============
// t0-only fences: __syncthreads() drains vmcnt per wave (stores in this XCD's
// L2); one t0 __threadfence (wb) publishes before the election atomic; the
// elected block t0-fences (inv) after winning, barrier, then reads.
__global__ __launch_bounds__(1024) void hist_cutoff_kernel(
    const float* __restrict__ scores, unsigned short* __restrict__ hist_part,
    unsigned int* __restrict__ ctrl)
{
    __shared__ unsigned int lh[NBINS];          // 8 KB
    __shared__ unsigned int pa[1024], pb[1024]; // 8 KB ping-pong
    __shared__ int lastf;
    const int t = threadIdx.x;

    lh[2 * t] = 0u; lh[2 * t + 1] = 0u;
    __syncthreads();

    for (int i = blockIdx.x * 1024 + t; i < N_CAND; i += HIST_BLOCKS * 1024) {
        float s = scores[i];
        if (s >= SCORE_THR) {
            int bin = (int)(s * (float)NBINS);
            bin = bin > (NBINS - 1) ? (NBINS - 1) : bin;
            atomicAdd(&lh[bin], 1u);   // LDS atomic only
        }
    }
    __syncthreads();
    // store part as packed u32 (two u16 bins), coalesced
    unsigned int* outp = (unsigned int*)(hist_part + (size_t)blockIdx.x * NBINS);
    outp[t] = (lh[2 * t] & 0xFFFFu) | (lh[2 * t + 1] << 16);
    __syncthreads();                                   // vmcnt drained -> stores in L2

    if (t == 0) {
        __threadfence();                               // release: wb this XCD's L2
        unsigned old = atomicAdd(&ctrl[C_HD], 1u);
        lastf = (old == HIST_BLOCKS - 1) ? 1 : 0;
    }
    __syncthreads();
    if (!lastf) return;
    if (t == 0) __threadfence();                       // acquire: invalidate caches
    __syncthreads();

    // ---- cutoff scan (elected block) ----
    const unsigned int* hp32 = (const unsigned int*)hist_part;
    unsigned b0 = 0u, b1 = 0u;
#pragma unroll 4
    for (int p = 0; p < HIST_BLOCKS; ++p) {
        unsigned v = hp32[p * 1024 + t];
        b0 += v & 0xFFFFu;
        b1 += v >> 16;
    }
    lh[2 * t] = b0; lh[2 * t + 1] = b1;
    pa[t] = b0 + b1;
    __syncthreads();

    // inclusive suffix scan, ping-pong (10 barriers)
    unsigned int* srcb = pa; unsigned int* dstb = pb;
    for (int off = 1; off < 1024; off <<= 1) {
        unsigned v = srcb[t] + ((t + off < 1024) ? srcb[t + off] : 0u);
        dstb[t] = v;
        __syncthreads();
        unsigned int* tmp = srcb; srcb = dstb; dstb = tmp;
    }
    unsigned St = srcb[t];
    unsigned Sn = (t < 1023) ? srcb[t + 1] : 0u;

    if (t == 0) {
        ctrl[C_CNT] = 0u;                   // reset compact counter (next dispatch)
        if (St < TARGET) ctrl[C_BIN] = 0u;  // total < TARGET -> keep all valid
    }
    // unique crossing thread: b* = max{b : suffix(b) >= TARGET}
    if (St >= TARGET && Sn < TARGET) {
        unsigned run = Sn + lh[2 * t + 1];
        ctrl[C_BIN] = (run >= TARGET) ? (unsigned)(2 * t + 1) : (unsigned)(2 * t);
    }
}

// box decode for one candidate (matches reference formulas, fp32)
__device__ inline float4 decode_box(const float* __restrict__ feats,
                                    const float* __restrict__ anchors, int ci)
{
    int a = ci % 5;
    int cell = ci / 5;
    int gx = cell % 76;
    int gy = (cell / 76) % 76;
    const float* f = feats + (long long)ci * 85;
    float bx = (1.0f / (1.0f + __expf(-f[0])) + (float)gx) / 76.0f;
    float by = (1.0f / (1.0f + __expf(-f[1])) + (float)gy) / 76.0f;
    float bw = __expf(f[2]) * anchors[2 * a]     / 76.0f;
    float bh = __expf(f[3]) * anchors[2 * a + 1] / 76.0f;
    return make_float4(by - bh * 0.5f, bx - bw * 0.5f,
                       by + bh * 0.5f, bx + bw * 0.5f);  // y1,x1,y2,x2
}

// ============ Kernel 3: compact (grid-stride) + elected sort-free NMS ============
__global__ __launch_bounds__(1024) void compact_nms_kernel(
    const float* __restrict__ scores, unsigned int* __restrict__ ctrl,
    float* __restrict__ lscore, int* __restrict__ lidx,
    const float* __restrict__ feats, const float* __restrict__ anchors,
    float* __restrict__ out)
{
    __shared__ unsigned long long wkey[16];
    __shared__ unsigned long long bkey;
    __shared__ float4 bbox;
    __shared__ int lastf;
    const int t = threadIdx.x;

    // ---- compact phase (grid-stride) ----
    const int cut = (int)ctrl[C_BIN];   // written by previous dispatch: coherent
    for (int i = blockIdx.x * 1024 + t; i < N_CAND; i += COMPACT_BLOCKS * 1024) {
        float sw = scores[i];
        if (sw >= SCORE_THR) {
            int bin = (int)(sw * (float)NBINS);
            bin = bin > (NBINS - 1) ? (NBINS - 1) : bin;
            if (bin >= cut) {
                unsigned pos = atomicAdd(&ctrl[C_CNT], 1u);
                if (pos < SMAX) { lscore[pos] = sw; lidx[pos] = i; }
            }
        }
    }
    __syncthreads();                                   // vmcnt drained -> stores in L2
    if (t == 0) {
        __threadfence();                               // release
        unsigned old = atomicAdd(&ctrl[C_CD], 1u);
        lastf = (old == COMPACT_BLOCKS - 1) ? 1 : 0;
    }
    __syncthreads();
    if (!lastf) return;
    if (t == 0) __threadfence();                       // acquire
    __syncthreads();

    // ---- NMS phase (1024 threads, 1 candidate/thread) ----
    unsigned cnt = ctrl[C_CNT];
    int n = (cnt < (unsigned)SMAX) ? (int)cnt : SMAX;

    unsigned long long key = 0ull;
    float4 mb = make_float4(0.f, 0.f, 0.f, 0.f);
    float  msc = 0.f, mcls = 0.f;
    unsigned midx = 0xFFFFFFFFu;
    bool aliveb = false;
    if (t < n) {
        msc  = lscore[t];
        midx = (unsigned)lidx[t];
        key  = ((unsigned long long)__float_as_uint(msc) << 32)
             | (unsigned long long)(0xFFFFFFFFu - midx);   // score desc, idx asc
        mb   = decode_box(feats, anchors, (int)midx);
        // class argmax from L3-resident feats (first-index tie-break)
        const float* fc = feats + (size_t)midx * 85 + 5;
        float bm = fc[0]; int cb = 0;
#pragma unroll 4
        for (int k = 1; k < 80; ++k) {
            float v = fc[k];
            if (v > bm) { bm = v; cb = k; }
        }
        mcls = (float)cb;
        aliveb = true;
    }

    for (int r = 0; r < 10; ++r) {
        unsigned long long k0 = aliveb ? key : 0ull;
#pragma unroll
        for (int msk = 32; msk > 0; msk >>= 1) {
            unsigned long long o = __shfl_xor(k0, msk);
            k0 = (o > k0) ? o : k0;
        }
        if ((t & 63) == 0) wkey[t >> 6] = k0;
        __syncthreads();
        if (t < 16) {
            unsigned long long v = wkey[t];
#pragma unroll
            for (int msk = 8; msk > 0; msk >>= 1) {
                unsigned long long o = __shfl_xor(v, msk);
                v = (o > v) ? o : v;
            }
            if (t == 0) bkey = v;
        }
        __syncthreads();

        unsigned long long wk = bkey;
        bool have = (wk != 0ull);
        unsigned widx = have ? (0xFFFFFFFFu - (unsigned)(wk & 0xFFFFFFFFull)) : 0xFFFFFFFFu;

        if (have && aliveb && midx == widx) {   // unique winner thread
            bbox = mb;
            out[r * 6 + 0] = mb.x;
            out[r * 6 + 1] = mb.y;
            out[r * 6 + 2] = mb.z;
            out[r * 6 + 3] = mb.w;
            out[r * 6 + 4] = msc;
            out[r * 6 + 5] = mcls;
            aliveb = false;
        }
        if (!have && t == 0) {
#pragma unroll
            for (int q = 0; q < 6; ++q) out[r * 6 + q] = 0.f;
        }
        __syncthreads();                        // bbox visible to all

        if (have && aliveb) {
            float4 ab = bbox;
            float aarea = fmaxf(ab.z - ab.x, 0.f) * fmaxf(ab.w - ab.y, 0.f);
            float iy1 = fmaxf(ab.x, mb.x);
            float ix1 = fmaxf(ab.y, mb.y);
            float iy2 = fminf(ab.z, mb.z);
            float ix2 = fminf(ab.w, mb.w);
            float inter = fmaxf(iy2 - iy1, 0.f) * fmaxf(ix2 - ix1, 0.f);
            float carea = fmaxf(mb.z - mb.x, 0.f) * fmaxf(mb.w - mb.y, 0.f);
            float iou = inter / (aarea + carea - inter + 1e-9f);
            if (iou > 0.5f) aliveb = false;
        }
    }
}

extern "C" void kernel_launch(void* const* d_in, const int* in_sizes, int n_in,
                              void* d_out, int out_size, void* d_ws, size_t ws_size,
                              hipStream_t stream) {
    const float* feats   = (const float*)d_in[0];
    const float* anchors = (const float*)d_in[1];
    char* ws = (char*)d_ws;

    unsigned int*   ctrl      = (unsigned int*)(ws + 0);
    unsigned short* hist_part = (unsigned short*)(ws + 256);
    float*          lscore    = (float*)(ws + 131328);
    int*            lidx      = (int*)(ws + 135424);
    float*          scores    = (float*)(ws + 139520);
    float*          out       = (float*)d_out;

    decode_kernel      <<<NT, 64, 0, stream>>>(feats, scores, ctrl);
    hist_cutoff_kernel <<<HIST_BLOCKS, 1024, 0, stream>>>(scores, hist_part, ctrl);
    compact_nms_kernel <<<COMPACT_BLOCKS, 1024, 0, stream>>>(scores, ctrl, lscore, lidx,
                                                             feats, anchors, out);
}

// Round 14
// 59.763 us; speedup vs baseline: 1.1941x; 1.1715x over previous
//
#include <hip/hip_runtime.h>
#include <stdint.h>

#define N_CAND 462080   // 16*76*76*5
#define NBINS  2048
#define HIST_BLOCKS 32
#define COMPACT_BLOCKS 64
#define TARGET 256u
#define SMAX   1024
#define SCORE_THR 0.02f
#define NB 7220         // decode blocks: 64 candidates each
// ctrl u32 indices, 64B apart (separate cache lines)
#define C_CNT 0    // compact count (hot atomic)
#define C_BIN 16   // cutoff bin
#define C_HD  32   // hist done-counter
#define C_CD  48   // compact done-counter

// ---------------- ws layout (bytes) ----------------
// ctrl      : 64 x u32       @ 0       end 256
// hist_part : 32 x 2048 u16  @ 256     end 131328
// lscore    : 1024 x f32     @ 131328  end 135424
// lidx      : 1024 x i32     @ 135424  end 139520
// scores    : N x f32        @ 139520  end 1987840
// cls       : N x u8         @ 1987840 end 2449920  (~2.45 MB)
// No memset dispatch: decode block 0 re-arms both done-counters every call;
// hist's elected block zeroes C_CNT and always writes C_BIN.
// => no dependence on initial ws content (harness poisons ws to 0xAA).

typedef const __attribute__((address_space(1))) uint32_t* gas1_u32;
typedef __attribute__((address_space(3))) uint32_t*       las3_u32;
#define GLOAD_LDS16(g, l) __builtin_amdgcn_global_load_lds( \
    (gas1_u32)(const void*)(g), (las3_u32)(void*)(l), 16, 0, 0)

// ============ Kernel 1: decode — 64-cand one-shot wave, half-tile overlap ============
// 21.76 KB LDS -> 7 blocks/CU (R10's proven config: 59.6 us total; R12/R13's
// cls-eviction + 32-cand variants regressed to ~70). New: issue all 22
// global_load_lds, vmcnt(11) -> compute half A (cands 0..31) while half B's
// loads land -> vmcnt(0) -> compute half B. Channel-split within a half:
// lanes (c, c+32) split candidate c's 80 classes; cross-half combine via
// shfl_xor(32) with exact first-index tie-break (h0 wins ties).
__global__ __launch_bounds__(64) void decode_kernel(
    const float* __restrict__ feats,
    float* __restrict__ scores, unsigned char* __restrict__ cls,
    unsigned int* __restrict__ ctrl)
{
    __shared__ __align__(16) float lds[64 * 85];   // 21760 B
    const int t = threadIdx.x;
    const int c = t & 31;        // candidate within half
    const int h = t >> 5;        // class-half (0: classes 0..39, 1: 40..79)

    if (blockIdx.x == 0 && t == 0) { ctrl[C_HD] = 0u; ctrl[C_CD] = 0u; }  // re-arm

    // stage 1360 float4 as two 680-float4 halves, 11 wave-issues each
    {
        const float4* __restrict__ src = (const float4*)(feats + (size_t)blockIdx.x * 5440);
        float4* dst = (float4*)lds;
#pragma unroll
        for (int i = 0; i < 10; ++i)
            GLOAD_LDS16(src + i * 64 + t, dst + i * 64 + t);
        if (t < 40) GLOAD_LDS16(src + 640 + t, dst + 640 + t);
#pragma unroll
        for (int i = 0; i < 10; ++i)
            GLOAD_LDS16(src + 680 + i * 64 + t, dst + 680 + i * 64 + t);
        if (t < 40) GLOAD_LDS16(src + 1320 + t, dst + 1320 + t);
    }

#pragma unroll
    for (int half = 0; half < 2; ++half) {
        if (half == 0)
            asm volatile("s_waitcnt vmcnt(11)" ::: "memory");  // half A landed
        else
            asm volatile("s_waitcnt vmcnt(0)" ::: "memory");   // half B landed
        __builtin_amdgcn_sched_barrier(0);

        const int cand = half * 32 + c;
        const float* f = lds + cand * 85;   // pairs (c,c+32) -> free 2-way banks
        const int kb = 5 + h * 40;

        // half-argmax over 40 class logits (serial first-index chain)
        float m = f[kb];
        int cb = h * 40;
#pragma unroll
        for (int k = 1; k < 40; ++k) {
            float v = f[kb + k];
            if (v > m) { m = v; cb = h * 40 + k; }
        }
        // cross-half combine (first-index: h0 wins ties)
        float mo = __shfl_xor(m, 32);
        int   cbo = __shfl_xor(cb, 32);
        float m0 = (h == 0) ? m : mo,  m1 = (h == 0) ? mo : m;
        int   c0 = (h == 0) ? cb : cbo, c1 = (h == 0) ? cbo : cb;
        float mall = fmaxf(m0, m1);
        int   cls_abs = (m0 >= m1) ? c0 : c1;

        // half-sum of exp(l - mall)
        float s0 = 0.f, s1 = 0.f, s2 = 0.f, s3 = 0.f;
#pragma unroll
        for (int k = 0; k < 40; k += 4) {
            s0 += __expf(f[kb + k + 0] - mall);
            s1 += __expf(f[kb + k + 1] - mall);
            s2 += __expf(f[kb + k + 2] - mall);
            s3 += __expf(f[kb + k + 3] - mall);
        }
        float sl = (s0 + s1) + (s2 + s3);
        float sall = sl + __shfl_xor(sl, 32);

        if (h == 0) {
            const int ci = blockIdx.x * 64 + cand;
            float conf = 1.0f / (1.0f + __expf(-f[4]));
            float score = conf / sall;                    // conf * max-softmax-prob
            scores[ci] = (score >= SCORE_THR) ? score : -1.0f;
            cls[ci] = (unsigned char)cls_abs;
        }
    }
}

// ============ Kernel 2: histogram + (elected last block) cutoff scan ============
// t0-only fences: __syncthreads() drains vmcnt per wave (stores in this XCD's
// L2); one t0 __threadfence (wb) publishes before the election atomic; the
// elected block t0-fences (inv) after winning, barrier, then reads.
__global__ __launch_bounds__(1024) void hist_cutoff_kernel(
    const float* __restrict__ scores, unsigned short* __restrict__ hist_part,
    unsigned int* __restrict__ ctrl)
{
    __shared__ unsigned int lh[NBINS];          // 8 KB
    __shared__ unsigned int pa[1024], pb[1024]; // 8 KB ping-pong
    __shared__ int lastf;
    const int t = threadIdx.x;

    lh[2 * t] = 0u; lh[2 * t + 1] = 0u;
    __syncthreads();

    for (int i = blockIdx.x * 1024 + t; i < N_CAND; i += HIST_BLOCKS * 1024) {
        float s = scores[i];
        if (s >= SCORE_THR) {
            int bin = (int)(s * (float)NBINS);
            bin = bin > (NBINS - 1) ? (NBINS - 1) : bin;
            atomicAdd(&lh[bin], 1u);   // LDS atomic only
        }
    }
    __syncthreads();
    // store part as packed u32 (two u16 bins), coalesced
    unsigned int* outp = (unsigned int*)(hist_part + (size_t)blockIdx.x * NBINS);
    outp[t] = (lh[2 * t] & 0xFFFFu) | (lh[2 * t + 1] << 16);
    __syncthreads();                                   // vmcnt drained -> stores in L2

    if (t == 0) {
        __threadfence();                               // release: wb this XCD's L2
        unsigned old = atomicAdd(&ctrl[C_HD], 1u);
        lastf = (old == HIST_BLOCKS - 1) ? 1 : 0;
    }
    __syncthreads();
    if (!lastf) return;
    if (t == 0) __threadfence();                       // acquire: invalidate caches
    __syncthreads();

    // ---- cutoff scan (elected block) ----
    const unsigned int* hp32 = (const unsigned int*)hist_part;
    unsigned b0 = 0u, b1 = 0u;
#pragma unroll 4
    for (int p = 0; p < HIST_BLOCKS; ++p) {
        unsigned v = hp32[p * 1024 + t];
        b0 += v & 0xFFFFu;
        b1 += v >> 16;
    }
    lh[2 * t] = b0; lh[2 * t + 1] = b1;
    pa[t] = b0 + b1;
    __syncthreads();

    // inclusive suffix scan, ping-pong (10 barriers)
    unsigned int* srcb = pa; unsigned int* dstb = pb;
    for (int off = 1; off < 1024; off <<= 1) {
        unsigned v = srcb[t] + ((t + off < 1024) ? srcb[t + off] : 0u);
        dstb[t] = v;
        __syncthreads();
        unsigned int* tmp = srcb; srcb = dstb; dstb = tmp;
    }
    unsigned St = srcb[t];
    unsigned Sn = (t < 1023) ? srcb[t + 1] : 0u;

    if (t == 0) {
        ctrl[C_CNT] = 0u;                   // reset compact counter (next dispatch)
        if (St < TARGET) ctrl[C_BIN] = 0u;  // total < TARGET -> keep all valid
    }
    // unique crossing thread: b* = max{b : suffix(b) >= TARGET}
    if (St >= TARGET && Sn < TARGET) {
        unsigned run = Sn + lh[2 * t + 1];
        ctrl[C_BIN] = (run >= TARGET) ? (unsigned)(2 * t + 1) : (unsigned)(2 * t);
    }
}

// box decode for one candidate (matches reference formulas, fp32)
__device__ inline float4 decode_box(const float* __restrict__ feats,
                                    const float* __restrict__ anchors, int ci)
{
    int a = ci % 5;
    int cell = ci / 5;
    int gx = cell % 76;
    int gy = (cell / 76) % 76;
    const float* f = feats + (long long)ci * 85;
    float bx = (1.0f / (1.0f + __expf(-f[0])) + (float)gx) / 76.0f;
    float by = (1.0f / (1.0f + __expf(-f[1])) + (float)gy) / 76.0f;
    float bw = __expf(f[2]) * anchors[2 * a]     / 76.0f;
    float bh = __expf(f[3]) * anchors[2 * a + 1] / 76.0f;
    return make_float4(by - bh * 0.5f, bx - bw * 0.5f,
                       by + bh * 0.5f, bx + bw * 0.5f);  // y1,x1,y2,x2
}

// ============ Kernel 3: compact (grid-stride) + elected sort-free NMS ============
__global__ __launch_bounds__(1024) void compact_nms_kernel(
    const float* __restrict__ scores, unsigned int* __restrict__ ctrl,
    float* __restrict__ lscore, int* __restrict__ lidx,
    const float* __restrict__ feats, const float* __restrict__ anchors,
    const unsigned char* __restrict__ cls, float* __restrict__ out)
{
    __shared__ unsigned long long wkey[16];
    __shared__ unsigned long long bkey;
    __shared__ float4 bbox;
    __shared__ int lastf;
    const int t = threadIdx.x;

    // ---- compact phase (grid-stride) ----
    const int cut = (int)ctrl[C_BIN];   // written by previous dispatch: coherent
    for (int i = blockIdx.x * 1024 + t; i < N_CAND; i += COMPACT_BLOCKS * 1024) {
        float sw = scores[i];
        if (sw >= SCORE_THR) {
            int bin = (int)(sw * (float)NBINS);
            bin = bin > (NBINS - 1) ? (NBINS - 1) : bin;
            if (bin >= cut) {
                unsigned pos = atomicAdd(&ctrl[C_CNT], 1u);
                if (pos < SMAX) { lscore[pos] = sw; lidx[pos] = i; }
            }
        }
    }
    __syncthreads();                                   // vmcnt drained -> stores in L2
    if (t == 0) {
        __threadfence();                               // release
        unsigned old = atomicAdd(&ctrl[C_CD], 1u);
        lastf = (old == COMPACT_BLOCKS - 1) ? 1 : 0;
    }
    __syncthreads();
    if (!lastf) return;
    if (t == 0) __threadfence();                       // acquire
    __syncthreads();

    // ---- NMS phase (1024 threads, 1 candidate/thread) ----
    unsigned cnt = ctrl[C_CNT];
    int n = (cnt < (unsigned)SMAX) ? (int)cnt : SMAX;

    unsigned long long key = 0ull;
    float4 mb = make_float4(0.f, 0.f, 0.f, 0.f);
    float  msc = 0.f, mcls = 0.f;
    unsigned midx = 0xFFFFFFFFu;
    bool aliveb = false;
    if (t < n) {
        msc  = lscore[t];
        midx = (unsigned)lidx[t];
        key  = ((unsigned long long)__float_as_uint(msc) << 32)
             | (unsigned long long)(0xFFFFFFFFu - midx);   // score desc, idx asc
        mb   = decode_box(feats, anchors, (int)midx);
        mcls = (float)cls[midx];
        aliveb = true;
    }

    for (int r = 0; r < 10; ++r) {
        unsigned long long k0 = aliveb ? key : 0ull;
#pragma unroll
        for (int msk = 32; msk > 0; msk >>= 1) {
            unsigned long long o = __shfl_xor(k0, msk);
            k0 = (o > k0) ? o : k0;
        }
        if ((t & 63) == 0) wkey[t >> 6] = k0;
        __syncthreads();
        if (t < 16) {
            unsigned long long v = wkey[t];
#pragma unroll
            for (int msk = 8; msk > 0; msk >>= 1) {
                unsigned long long o = __shfl_xor(v, msk);
                v = (o > v) ? o : v;
            }
            if (t == 0) bkey = v;
        }
        __syncthreads();

        unsigned long long wk = bkey;
        bool have = (wk != 0ull);
        unsigned widx = have ? (0xFFFFFFFFu - (unsigned)(wk & 0xFFFFFFFFull)) : 0xFFFFFFFFu;

        if (have && aliveb && midx == widx) {   // unique winner thread
            bbox = mb;
            out[r * 6 + 0] = mb.x;
            out[r * 6 + 1] = mb.y;
            out[r * 6 + 2] = mb.z;
            out[r * 6 + 3] = mb.w;
            out[r * 6 + 4] = msc;
            out[r * 6 + 5] = mcls;
            aliveb = false;
        }
        if (!have && t == 0) {
#pragma unroll
            for (int q = 0; q < 6; ++q) out[r * 6 + q] = 0.f;
        }
        __syncthreads();                        // bbox visible to all

        if (have && aliveb) {
            float4 ab = bbox;
            float aarea = fmaxf(ab.z - ab.x, 0.f) * fmaxf(ab.w - ab.y, 0.f);
            float iy1 = fmaxf(ab.x, mb.x);
            float ix1 = fmaxf(ab.y, mb.y);
            float iy2 = fminf(ab.z, mb.z);
            float ix2 = fminf(ab.w, mb.w);
            float inter = fmaxf(iy2 - iy1, 0.f) * fmaxf(ix2 - ix1, 0.f);
            float carea = fmaxf(mb.z - mb.x, 0.f) * fmaxf(mb.w - mb.y, 0.f);
            float iou = inter / (aarea + carea - inter + 1e-9f);
            if (iou > 0.5f) aliveb = false;
        }
    }
}

extern "C" void kernel_launch(void* const* d_in, const int* in_sizes, int n_in,
                              void* d_out, int out_size, void* d_ws, size_t ws_size,
                              hipStream_t stream) {
    const float* feats   = (const float*)d_in[0];
    const float* anchors = (const float*)d_in[1];
    char* ws = (char*)d_ws;

    unsigned int*   ctrl      = (unsigned int*)(ws + 0);
    unsigned short* hist_part = (unsigned short*)(ws + 256);
    float*          lscore    = (float*)(ws + 131328);
    int*            lidx      = (int*)(ws + 135424);
    float*          scores    = (float*)(ws + 139520);
    unsigned char*  cls       = (unsigned char*)(ws + 1987840);
    float*          out       = (float*)d_out;

    decode_kernel      <<<NB, 64, 0, stream>>>(feats, scores, cls, ctrl);
    hist_cutoff_kernel <<<HIST_BLOCKS, 1024, 0, stream>>>(scores, hist_part, ctrl);
    compact_nms_kernel <<<COMPACT_BLOCKS, 1024, 0, stream>>>(scores, ctrl, lscore, lidx,
                                                             feats, anchors, cls, out);
}

// Round 16
// 58.548 us; speedup vs baseline: 1.2189x; 1.0208x over previous
//
#include <hip/hip_runtime.h>
#include <stdint.h>

#define N_CAND 462080   // 16*76*76*5
#define NBINS  2048
#define HIST_BLOCKS 32
#define COMPACT_BLOCKS 64
#define TARGET 256u
#define SMAX   1024
#define SCORE_THR 0.02f
#define NT 14440        // decode blocks: 32 candidates each (14440*32 = 462080)
#define TILEF 2720      // floats per tile (32*85)
// ctrl u32 indices, 64B apart (separate cache lines)
#define C_CNT 0    // compact count (hot atomic)
#define C_BIN 16   // cutoff bin
#define C_HD  32   // hist done-counter
#define C_CD  48   // compact done-counter

// ---------------- ws layout (bytes) ----------------
// ctrl      : 64 x u32       @ 0       end 256
// hist_part : 32 x 2048 u16  @ 256     end 131328
// lscore    : 1024 x f32     @ 131328  end 135424
// lidx      : 1024 x i32     @ 135424  end 139520
// scores    : N x f32        @ 139520  end 1987840
// cls       : N x u8         @ 1987840 end 2449920  (~2.45 MB)
// No memset dispatch: decode block 0 re-arms both done-counters every call;
// hist's elected block zeroes C_CNT and always writes C_BIN.

// ============ Kernel 1: decode — REGISTER-staged (A/B vs global_load_lds) ============
// R10/R12/R13/R14 all used global_load_lds staging and all landed ~59.6-60
// (cls-adjusted) regardless of occupancy/pipelining -> suspect gload_lds
// per-CU throughput is the invariant ceiling. This round: classic coalesced
// register staging (11x global_load_dwordx4 -> 11x ds_write_b128), 32-cand
// one-wave blocks, 10.88 KB LDS -> 14 blocks/CU. Compute: R14's channel-split
// (lanes c, c+32 split candidate c's 80 classes), cls argmax in decode.
__global__ __launch_bounds__(64) void decode_kernel(
    const float* __restrict__ feats,
    float* __restrict__ scores, unsigned char* __restrict__ cls,
    unsigned int* __restrict__ ctrl)
{
    __shared__ __align__(16) float lds[TILEF];   // 10880 B
    const int t = threadIdx.x;
    const int c = t & 31;        // candidate within tile
    const int h = t >> 5;        // class-half (0: classes 0..39, 1: 40..79)

    if (blockIdx.x == 0 && t == 0) { ctrl[C_HD] = 0u; ctrl[C_CD] = 0u; }  // re-arm

    // coalesced register staging: 680 float4 = 10 full wave-rounds + 40-lane tail
    {
        const float4* __restrict__ src = (const float4*)(feats + (size_t)blockIdx.x * TILEF);
        float4* dst = (float4*)lds;
        float4 v[10];
#pragma unroll
        for (int i = 0; i < 10; ++i) v[i] = src[i * 64 + t];
        float4 vt;
        if (t < 40) vt = src[640 + t];
#pragma unroll
        for (int i = 0; i < 10; ++i) dst[i * 64 + t] = v[i];   // hits all 32 banks: no extra cost
        if (t < 40) dst[640 + t] = vt;
    }
    // cross-lane LDS dependency: fence ds_writes before other lanes' reads (rule #18)
    asm volatile("s_waitcnt lgkmcnt(0)" ::: "memory");
    __builtin_amdgcn_sched_barrier(0);

    const float* f = lds + c * 85;   // pairs (c,c+32) same bank = free 2-way
    const int kb = 5 + h * 40;

    // half-argmax over 40 class logits (serial first-index chain)
    float m = f[kb];
    int cb = h * 40;
#pragma unroll
    for (int k = 1; k < 40; ++k) {
        float v = f[kb + k];
        if (v > m) { m = v; cb = h * 40 + k; }
    }
    // cross-half combine (first-index: h0 wins ties)
    float mo = __shfl_xor(m, 32);
    int   cbo = __shfl_xor(cb, 32);
    float m0 = (h == 0) ? m : mo,  m1 = (h == 0) ? mo : m;
    int   c0 = (h == 0) ? cb : cbo, c1 = (h == 0) ? cbo : cb;
    float mall = fmaxf(m0, m1);
    int   cls_abs = (m0 >= m1) ? c0 : c1;

    // half-sum of exp(l - mall)
    float s0 = 0.f, s1 = 0.f, s2 = 0.f, s3 = 0.f;
#pragma unroll
    for (int k = 0; k < 40; k += 4) {
        s0 += __expf(f[kb + k + 0] - mall);
        s1 += __expf(f[kb + k + 1] - mall);
        s2 += __expf(f[kb + k + 2] - mall);
        s3 += __expf(f[kb + k + 3] - mall);
    }
    float sl = (s0 + s1) + (s2 + s3);
    float sall = sl + __shfl_xor(sl, 32);

    if (h == 0) {
        const int ci = blockIdx.x * 32 + c;
        float conf = 1.0f / (1.0f + __expf(-f[4]));
        float score = conf / sall;                    // conf * max-softmax-prob
        scores[ci] = (score >= SCORE_THR) ? score : -1.0f;
        cls[ci] = (unsigned char)cls_abs;
    }
}

// ============ Kernel 2: histogram + (elected last block) cutoff scan ============
__global__ __launch_bounds__(1024) void hist_cutoff_kernel(
    const float* __restrict__ scores, unsigned short* __restrict__ hist_part,
    unsigned int* __restrict__ ctrl)
{
    __shared__ unsigned int lh[NBINS];          // 8 KB
    __shared__ unsigned int pa[1024], pb[1024]; // 8 KB ping-pong
    __shared__ int lastf;
    const int t = threadIdx.x;

    lh[2 * t] = 0u; lh[2 * t + 1] = 0u;
    __syncthreads();

    for (int i = blockIdx.x * 1024 + t; i < N_CAND; i += HIST_BLOCKS * 1024) {
        float s = scores[i];
        if (s >= SCORE_THR) {
            int bin = (int)(s * (float)NBINS);
            bin = bin > (NBINS - 1) ? (NBINS - 1) : bin;
            atomicAdd(&lh[bin], 1u);   // LDS atomic only
        }
    }
    __syncthreads();
    unsigned int* outp = (unsigned int*)(hist_part + (size_t)blockIdx.x * NBINS);
    outp[t] = (lh[2 * t] & 0xFFFFu) | (lh[2 * t + 1] << 16);
    __syncthreads();                                   // vmcnt drained -> stores in L2

    if (t == 0) {
        __threadfence();                               // release: wb this XCD's L2
        unsigned old = atomicAdd(&ctrl[C_HD], 1u);
        lastf = (old == HIST_BLOCKS - 1) ? 1 : 0;
    }
    __syncthreads();
    if (!lastf) return;
    if (t == 0) __threadfence();                       // acquire: invalidate caches
    __syncthreads();

    // ---- cutoff scan (elected block) ----
    const unsigned int* hp32 = (const unsigned int*)hist_part;
    unsigned b0 = 0u, b1 = 0u;
#pragma unroll 4
    for (int p = 0; p < HIST_BLOCKS; ++p) {
        unsigned v = hp32[p * 1024 + t];
        b0 += v & 0xFFFFu;
        b1 += v >> 16;
    }
    lh[2 * t] = b0; lh[2 * t + 1] = b1;
    pa[t] = b0 + b1;
    __syncthreads();

    unsigned int* srcb = pa; unsigned int* dstb = pb;
    for (int off = 1; off < 1024; off <<= 1) {
        unsigned v = srcb[t] + ((t + off < 1024) ? srcb[t + off] : 0u);
        dstb[t] = v;
        __syncthreads();
        unsigned int* tmp = srcb; srcb = dstb; dstb = tmp;
    }
    unsigned St = srcb[t];
    unsigned Sn = (t < 1023) ? srcb[t + 1] : 0u;

    if (t == 0) {
        ctrl[C_CNT] = 0u;
        if (St < TARGET) ctrl[C_BIN] = 0u;
    }
    if (St >= TARGET && Sn < TARGET) {
        unsigned run = Sn + lh[2 * t + 1];
        ctrl[C_BIN] = (run >= TARGET) ? (unsigned)(2 * t + 1) : (unsigned)(2 * t);
    }
}

// box decode for one candidate (matches reference formulas, fp32)
__device__ inline float4 decode_box(const float* __restrict__ feats,
                                    const float* __restrict__ anchors, int ci)
{
    int a = ci % 5;
    int cell = ci / 5;
    int gx = cell % 76;
    int gy = (cell / 76) % 76;
    const float* f = feats + (long long)ci * 85;
    float bx = (1.0f / (1.0f + __expf(-f[0])) + (float)gx) / 76.0f;
    float by = (1.0f / (1.0f + __expf(-f[1])) + (float)gy) / 76.0f;
    float bw = __expf(f[2]) * anchors[2 * a]     / 76.0f;
    float bh = __expf(f[3]) * anchors[2 * a + 1] / 76.0f;
    return make_float4(by - bh * 0.5f, bx - bw * 0.5f,
                       by + bh * 0.5f, bx + bw * 0.5f);  // y1,x1,y2,x2
}

// ============ Kernel 3: compact (grid-stride) + elected sort-free NMS ============
__global__ __launch_bounds__(1024) void compact_nms_kernel(
    const float* __restrict__ scores, unsigned int* __restrict__ ctrl,
    float* __restrict__ lscore, int* __restrict__ lidx,
    const float* __restrict__ feats, const float* __restrict__ anchors,
    const unsigned char* __restrict__ cls, float* __restrict__ out)
{
    __shared__ unsigned long long wkey[16];
    __shared__ unsigned long long bkey;
    __shared__ float4 bbox;
    __shared__ int lastf;
    const int t = threadIdx.x;

    const int cut = (int)ctrl[C_BIN];
    for (int i = blockIdx.x * 1024 + t; i < N_CAND; i += COMPACT_BLOCKS * 1024) {
        float sw = scores[i];
        if (sw >= SCORE_THR) {
            int bin = (int)(sw * (float)NBINS);
            bin = bin > (NBINS - 1) ? (NBINS - 1) : bin;
            if (bin >= cut) {
                unsigned pos = atomicAdd(&ctrl[C_CNT], 1u);
                if (pos < SMAX) { lscore[pos] = sw; lidx[pos] = i; }
            }
        }
    }
    __syncthreads();
    if (t == 0) {
        __threadfence();                               // release
        unsigned old = atomicAdd(&ctrl[C_CD], 1u);
        lastf = (old == COMPACT_BLOCKS - 1) ? 1 : 0;
    }
    __syncthreads();
    if (!lastf) return;
    if (t == 0) __threadfence();                       // acquire
    __syncthreads();

    // ---- NMS phase (1024 threads, 1 candidate/thread) ----
    unsigned cnt = ctrl[C_CNT];
    int n = (cnt < (unsigned)SMAX) ? (int)cnt : SMAX;

    unsigned long long key = 0ull;
    float4 mb = make_float4(0.f, 0.f, 0.f, 0.f);
    float  msc = 0.f, mcls = 0.f;
    unsigned midx = 0xFFFFFFFFu;
    bool aliveb = false;
    if (t < n) {
        msc  = lscore[t];
        midx = (unsigned)lidx[t];
        key  = ((unsigned long long)__float_as_uint(msc) << 32)
             | (unsigned long long)(0xFFFFFFFFu - midx);   // score desc, idx asc
        mb   = decode_box(feats, anchors, (int)midx);
        mcls = (float)cls[midx];
        aliveb = true;
    }

    for (int r = 0; r < 10; ++r) {
        unsigned long long k0 = aliveb ? key : 0ull;
#pragma unroll
        for (int msk = 32; msk > 0; msk >>= 1) {
            unsigned long long o = __shfl_xor(k0, msk);
            k0 = (o > k0) ? o : k0;
        }
        if ((t & 63) == 0) wkey[t >> 6] = k0;
        __syncthreads();
        if (t < 16) {
            unsigned long long v = wkey[t];
#pragma unroll
            for (int msk = 8; msk > 0; msk >>= 1) {
                unsigned long long o = __shfl_xor(v, msk);
                v = (o > v) ? o : v;
            }
            if (t == 0) bkey = v;
        }
        __syncthreads();

        unsigned long long wk = bkey;
        bool have = (wk != 0ull);
        unsigned widx = have ? (0xFFFFFFFFu - (unsigned)(wk & 0xFFFFFFFFull)) : 0xFFFFFFFFu;

        if (have && aliveb && midx == widx) {   // unique winner thread
            bbox = mb;
            out[r * 6 + 0] = mb.x;
            out[r * 6 + 1] = mb.y;
            out[r * 6 + 2] = mb.z;
            out[r * 6 + 3] = mb.w;
            out[r * 6 + 4] = msc;
            out[r * 6 + 5] = mcls;
            aliveb = false;
        }
        if (!have && t == 0) {
#pragma unroll
            for (int q = 0; q < 6; ++q) out[r * 6 + q] = 0.f;
        }
        __syncthreads();                        // bbox visible to all

        if (have && aliveb) {
            float4 ab = bbox;
            float aarea = fmaxf(ab.z - ab.x, 0.f) * fmaxf(ab.w - ab.y, 0.f);
            float iy1 = fmaxf(ab.x, mb.x);
            float ix1 = fmaxf(ab.y, mb.y);
            float iy2 = fminf(ab.z, mb.z);
            float ix2 = fminf(ab.w, mb.w);
            float inter = fmaxf(iy2 - iy1, 0.f) * fmaxf(ix2 - ix1, 0.f);
            float carea = fmaxf(mb.z - mb.x, 0.f) * fmaxf(mb.w - mb.y, 0.f);
            float iou = inter / (aarea + carea - inter + 1e-9f);
            if (iou > 0.5f) aliveb = false;
        }
    }
}

extern "C" void kernel_launch(void* const* d_in, const int* in_sizes, int n_in,
                              void* d_out, int out_size, void* d_ws, size_t ws_size,
                              hipStream_t stream) {
    const float* feats   = (const float*)d_in[0];
    const float* anchors = (const float*)d_in[1];
    char* ws = (char*)d_ws;

    unsigned int*   ctrl      = (unsigned int*)(ws + 0);
    unsigned short* hist_part = (unsigned short*)(ws + 256);
    float*          lscore    = (float*)(ws + 131328);
    int*            lidx      = (int*)(ws + 135424);
    float*          scores    = (float*)(ws + 139520);
    unsigned char*  cls       = (unsigned char*)(ws + 1987840);
    float*          out       = (float*)d_out;

    decode_kernel      <<<NT, 64, 0, stream>>>(feats, scores, cls, ctrl);
    hist_cutoff_kernel <<<HIST_BLOCKS, 1024, 0, stream>>>(scores, hist_part, ctrl);
    compact_nms_kernel <<<COMPACT_BLOCKS, 1024, 0, stream>>>(scores, ctrl, lscore, lidx,
                                                             feats, anchors, cls, out);
}

// Round 17
// 57.885 us; speedup vs baseline: 1.2329x; 1.0114x over previous
//
#include <hip/hip_runtime.h>
#include <stdint.h>

#define N_CAND 462080   // 16*76*76*5
#define NBINS  2048
#define HPAD   16       // one hist bin per 64B line
#define HIST_BLOCKS 32
#define COMPACT_BLOCKS 64
#define TARGET 256u
#define SMAX   1024
#define SCORE_THR 0.02f
#define TILEF 2720      // floats per 32-cand tile
#define DB 3610         // decode blocks: 4 tiles each (3610*4*32 = 462080)
// ctrl u32 indices, 64B apart (separate cache lines)
#define C_CNT 0    // compact count (hot atomic)
#define C_BIN 16   // cutoff bin
#define C_HD  32   // hist done-counter
#define C_CD  48   // compact done-counter

// ---------------- ws layout (bytes) ----------------
// ctrl   : 64 x u32        @ 0       end 256
// hist   : 2048 x 16 u32   @ 256     end 131328  (padded; zeroed by decode blk 0)
// lscore : 1024 x f32      @ 131328  end 135424
// lidx   : 1024 x i32      @ 135424  end 139520
// scores : N x f32         @ 139520  end 1987840
// cls    : N x u8          @ 1987840 end 2449920  (~2.45 MB)
// No memset dispatch: decode block 0 re-arms done-counters AND zeroes hist
// every call; elected hist block zeroes C_CNT and always writes C_BIN.

// ============ Kernel 1: decode — 256-thr blocks, 4 autonomous waves ============
// A/B vs R16 (64-thr blocks, same algorithm, 58.5us): tests whether workgroup
// dispatch count (14440 -> 3610) is the hidden decode cost. Each wave stages
// its own 32-cand tile (register staging: 11x dwordx4 -> 11x ds_write_b128)
// and computes independently -- NO barriers. Channel-split: lanes c, c+32
// split candidate c's 80 classes; cls argmax in decode (R13 lesson).
__global__ __launch_bounds__(256) void decode_kernel(
    const float* __restrict__ feats,
    float* __restrict__ scores, unsigned char* __restrict__ cls,
    unsigned int* __restrict__ ctrl, unsigned int* __restrict__ hist)
{
    __shared__ __align__(16) float lds[4 * TILEF];   // 43520 B -> 3 blocks/CU
    const int t = threadIdx.x;
    const int w = t >> 6;        // wave 0..3
    const int lane = t & 63;
    const int c = lane & 31;     // candidate within tile
    const int h = lane >> 5;     // class-half (0: 0..39, 1: 40..79)

    if (blockIdx.x == 0) {       // re-arm counters + zero padded hist (next kernel reads)
        if (t == 0) { ctrl[C_HD] = 0u; ctrl[C_CD] = 0u; }
#pragma unroll
        for (int i = 0; i < 8; ++i) hist[(t * 8 + i) * HPAD] = 0u;
    }

    const int tile = blockIdx.x * 4 + w;
    float* myl = lds + w * TILEF;
    {
        const float4* __restrict__ src = (const float4*)(feats + (size_t)tile * TILEF);
        float4* dst = (float4*)myl;
        float4 v[10];
#pragma unroll
        for (int i = 0; i < 10; ++i) v[i] = src[i * 64 + lane];
        float4 vt;
        if (lane < 40) vt = src[640 + lane];
#pragma unroll
        for (int i = 0; i < 10; ++i) dst[i * 64 + lane] = v[i];
        if (lane < 40) dst[640 + lane] = vt;
    }
    // fence ds_writes before cross-lane LDS reads (rule #18); per-wave only
    asm volatile("s_waitcnt lgkmcnt(0)" ::: "memory");
    __builtin_amdgcn_sched_barrier(0);

    const float* f = myl + c * 85;   // pairs (c,c+32) same bank = free 2-way
    const int kb = 5 + h * 40;

    // half-argmax over 40 class logits (serial first-index chain)
    float m = f[kb];
    int cb = h * 40;
#pragma unroll
    for (int k = 1; k < 40; ++k) {
        float v = f[kb + k];
        if (v > m) { m = v; cb = h * 40 + k; }
    }
    // cross-half combine (first-index: h0 wins ties)
    float mo = __shfl_xor(m, 32);
    int   cbo = __shfl_xor(cb, 32);
    float m0 = (h == 0) ? m : mo,  m1 = (h == 0) ? mo : m;
    int   c0 = (h == 0) ? cb : cbo, c1 = (h == 0) ? cbo : cb;
    float mall = fmaxf(m0, m1);
    int   cls_abs = (m0 >= m1) ? c0 : c1;

    // half-sum of exp(l - mall)
    float s0 = 0.f, s1 = 0.f, s2 = 0.f, s3 = 0.f;
#pragma unroll
    for (int k = 0; k < 40; k += 4) {
        s0 += __expf(f[kb + k + 0] - mall);
        s1 += __expf(f[kb + k + 1] - mall);
        s2 += __expf(f[kb + k + 2] - mall);
        s3 += __expf(f[kb + k + 3] - mall);
    }
    float sl = (s0 + s1) + (s2 + s3);
    float sall = sl + __shfl_xor(sl, 32);

    if (h == 0) {
        const int ci = tile * 32 + c;
        float conf = 1.0f / (1.0f + __expf(-f[4]));
        float score = conf / sall;                    // conf * max-softmax-prob
        scores[ci] = (score >= SCORE_THR) ? score : -1.0f;
        cls[ci] = (unsigned char)cls_abs;
    }
}

// ============ Kernel 2: histogram (spread global-atomic flush) + elected cutoff ============
// Flush: <=2 atomics/thread to 64B-padded bins (<=32 collisions/bin across the
// whole grid -- fully parallel in L2, unlike R2's hot-bin disaster). Elected
// scan then reads only 8KB (2 loads/thread) instead of 128KB of parts.
__global__ __launch_bounds__(1024) void hist_cutoff_kernel(
    const float* __restrict__ scores, unsigned int* __restrict__ hist,
    unsigned int* __restrict__ ctrl)
{
    __shared__ unsigned int lh[NBINS];          // 8 KB
    __shared__ unsigned int pa[1024], pb[1024]; // 8 KB ping-pong
    __shared__ int lastf;
    const int t = threadIdx.x;

    lh[2 * t] = 0u; lh[2 * t + 1] = 0u;
    __syncthreads();

    for (int i = blockIdx.x * 1024 + t; i < N_CAND; i += HIST_BLOCKS * 1024) {
        float s = scores[i];
        if (s >= SCORE_THR) {
            int bin = (int)(s * (float)NBINS);
            bin = bin > (NBINS - 1) ? (NBINS - 1) : bin;
            atomicAdd(&lh[bin], 1u);   // LDS atomic only
        }
    }
    __syncthreads();
    unsigned v0 = lh[2 * t], v1 = lh[2 * t + 1];
    if (v0) atomicAdd(&hist[(2 * t) * HPAD], v0);      // device-scope, spread
    if (v1) atomicAdd(&hist[(2 * t + 1) * HPAD], v1);
    __syncthreads();                                   // atomics issued & drained

    if (t == 0) {
        __threadfence();                               // release
        unsigned old = atomicAdd(&ctrl[C_HD], 1u);
        lastf = (old == HIST_BLOCKS - 1) ? 1 : 0;
    }
    __syncthreads();
    if (!lastf) return;
    if (t == 0) __threadfence();                       // acquire
    __syncthreads();

    // ---- cutoff scan (elected block): 2 loads/thread ----
    unsigned b0 = hist[(2 * t) * HPAD];
    unsigned b1 = hist[(2 * t + 1) * HPAD];
    lh[2 * t] = b0; lh[2 * t + 1] = b1;
    pa[t] = b0 + b1;
    __syncthreads();

    // inclusive suffix scan, ping-pong (10 barriers)
    unsigned int* srcb = pa; unsigned int* dstb = pb;
    for (int off = 1; off < 1024; off <<= 1) {
        unsigned v = srcb[t] + ((t + off < 1024) ? srcb[t + off] : 0u);
        dstb[t] = v;
        __syncthreads();
        unsigned int* tmp = srcb; srcb = dstb; dstb = tmp;
    }
    unsigned St = srcb[t];
    unsigned Sn = (t < 1023) ? srcb[t + 1] : 0u;

    if (t == 0) {
        ctrl[C_CNT] = 0u;                   // reset compact counter (next dispatch)
        if (St < TARGET) ctrl[C_BIN] = 0u;  // total < TARGET -> keep all valid
    }
    // unique crossing thread: b* = max{b : suffix(b) >= TARGET}
    if (St >= TARGET && Sn < TARGET) {
        unsigned run = Sn + lh[2 * t + 1];
        ctrl[C_BIN] = (run >= TARGET) ? (unsigned)(2 * t + 1) : (unsigned)(2 * t);
    }
}

// box decode for one candidate (matches reference formulas, fp32)
__device__ inline float4 decode_box(const float* __restrict__ feats,
                                    const float* __restrict__ anchors, int ci)
{
    int a = ci % 5;
    int cell = ci / 5;
    int gx = cell % 76;
    int gy = (cell / 76) % 76;
    const float* f = feats + (long long)ci * 85;
    float bx = (1.0f / (1.0f + __expf(-f[0])) + (float)gx) / 76.0f;
    float by = (1.0f / (1.0f + __expf(-f[1])) + (float)gy) / 76.0f;
    float bw = __expf(f[2]) * anchors[2 * a]     / 76.0f;
    float bh = __expf(f[3]) * anchors[2 * a + 1] / 76.0f;
    return make_float4(by - bh * 0.5f, bx - bw * 0.5f,
                       by + bh * 0.5f, bx + bw * 0.5f);  // y1,x1,y2,x2
}

// ============ Kernel 3: compact (grid-stride) + elected sort-free NMS ============
__global__ __launch_bounds__(1024) void compact_nms_kernel(
    const float* __restrict__ scores, unsigned int* __restrict__ ctrl,
    float* __restrict__ lscore, int* __restrict__ lidx,
    const float* __restrict__ feats, const float* __restrict__ anchors,
    const unsigned char* __restrict__ cls, float* __restrict__ out)
{
    __shared__ unsigned long long wkey[16];
    __shared__ unsigned long long bkey;
    __shared__ float4 bbox;
    __shared__ int lastf;
    const int t = threadIdx.x;

    const int cut = (int)ctrl[C_BIN];
    for (int i = blockIdx.x * 1024 + t; i < N_CAND; i += COMPACT_BLOCKS * 1024) {
        float sw = scores[i];
        if (sw >= SCORE_THR) {
            int bin = (int)(sw * (float)NBINS);
            bin = bin > (NBINS - 1) ? (NBINS - 1) : bin;
            if (bin >= cut) {
                unsigned pos = atomicAdd(&ctrl[C_CNT], 1u);
                if (pos < SMAX) { lscore[pos] = sw; lidx[pos] = i; }
            }
        }
    }
    __syncthreads();
    if (t == 0) {
        __threadfence();                               // release
        unsigned old = atomicAdd(&ctrl[C_CD], 1u);
        lastf = (old == COMPACT_BLOCKS - 1) ? 1 : 0;
    }
    __syncthreads();
    if (!lastf) return;
    if (t == 0) __threadfence();                       // acquire
    __syncthreads();

    // ---- NMS phase (1024 threads, 1 candidate/thread) ----
    unsigned cnt = ctrl[C_CNT];
    int n = (cnt < (unsigned)SMAX) ? (int)cnt : SMAX;

    unsigned long long key = 0ull;
    float4 mb = make_float4(0.f, 0.f, 0.f, 0.f);
    float  msc = 0.f, mcls = 0.f;
    unsigned midx = 0xFFFFFFFFu;
    bool aliveb = false;
    if (t < n) {
        msc  = lscore[t];
        midx = (unsigned)lidx[t];
        key  = ((unsigned long long)__float_as_uint(msc) << 32)
             | (unsigned long long)(0xFFFFFFFFu - midx);   // score desc, idx asc
        mb   = decode_box(feats, anchors, (int)midx);
        mcls = (float)cls[midx];
        aliveb = true;
    }

    for (int r = 0; r < 10; ++r) {
        unsigned long long k0 = aliveb ? key : 0ull;
#pragma unroll
        for (int msk = 32; msk > 0; msk >>= 1) {
            unsigned long long o = __shfl_xor(k0, msk);
            k0 = (o > k0) ? o : k0;
        }
        if ((t & 63) == 0) wkey[t >> 6] = k0;
        __syncthreads();
        if (t < 16) {
            unsigned long long v = wkey[t];
#pragma unroll
            for (int msk = 8; msk > 0; msk >>= 1) {
                unsigned long long o = __shfl_xor(v, msk);
                v = (o > v) ? o : v;
            }
            if (t == 0) bkey = v;
        }
        __syncthreads();

        unsigned long long wk = bkey;
        bool have = (wk != 0ull);
        unsigned widx = have ? (0xFFFFFFFFu - (unsigned)(wk & 0xFFFFFFFFull)) : 0xFFFFFFFFu;

        if (have && aliveb && midx == widx) {   // unique winner thread
            bbox = mb;
            out[r * 6 + 0] = mb.x;
            out[r * 6 + 1] = mb.y;
            out[r * 6 + 2] = mb.z;
            out[r * 6 + 3] = mb.w;
            out[r * 6 + 4] = msc;
            out[r * 6 + 5] = mcls;
            aliveb = false;
        }
        if (!have && t == 0) {
#pragma unroll
            for (int q = 0; q < 6; ++q) out[r * 6 + q] = 0.f;
        }
        __syncthreads();                        // bbox visible to all

        if (have && aliveb) {
            float4 ab = bbox;
            float aarea = fmaxf(ab.z - ab.x, 0.f) * fmaxf(ab.w - ab.y, 0.f);
            float iy1 = fmaxf(ab.x, mb.x);
            float ix1 = fmaxf(ab.y, mb.y);
            float iy2 = fminf(ab.z, mb.z);
            float ix2 = fminf(ab.w, mb.w);
            float inter = fmaxf(iy2 - iy1, 0.f) * fmaxf(ix2 - ix1, 0.f);
            float carea = fmaxf(mb.z - mb.x, 0.f) * fmaxf(mb.w - mb.y, 0.f);
            float iou = inter / (aarea + carea - inter + 1e-9f);
            if (iou > 0.5f) aliveb = false;
        }
    }
}

extern "C" void kernel_launch(void* const* d_in, const int* in_sizes, int n_in,
                              void* d_out, int out_size, void* d_ws, size_t ws_size,
                              hipStream_t stream) {
    const float* feats   = (const float*)d_in[0];
    const float* anchors = (const float*)d_in[1];
    char* ws = (char*)d_ws;

    unsigned int*   ctrl   = (unsigned int*)(ws + 0);
    unsigned int*   hist   = (unsigned int*)(ws + 256);
    float*          lscore = (float*)(ws + 131328);
    int*            lidx   = (int*)(ws + 135424);
    float*          scores = (float*)(ws + 139520);
    unsigned char*  cls    = (unsigned char*)(ws + 1987840);
    float*          out    = (float*)d_out;

    decode_kernel      <<<DB, 256, 0, stream>>>(feats, scores, cls, ctrl, hist);
    hist_cutoff_kernel <<<HIST_BLOCKS, 1024, 0, stream>>>(scores, hist, ctrl);
    compact_nms_kernel <<<COMPACT_BLOCKS, 1024, 0, stream>>>(scores, ctrl, lscore, lidx,
                                                             feats, anchors, cls, out);
}